// Round 7
// baseline (421.385 us; speedup 1.0000x reference)
//
#include <hip/hip_runtime.h>
#include <cfloat>
#include <cstddef>
#include <cstdint>

#define BATCH 8
#define CDIM  256
#define NTOK  2304   // 48*48

typedef float    f32x4 __attribute__((ext_vector_type(4)));
typedef _Float16 f16x8 __attribute__((ext_vector_type(8)));
typedef _Float16 f16x4 __attribute__((ext_vector_type(4)));

#define MFMA16(a, b, c) __builtin_amdgcn_mfma_f32_16x16x32_f16(a, b, c, 0, 0, 0)

__device__ __forceinline__ void gl_lds16(const void* g, void* l) {
    __builtin_amdgcn_global_load_lds(
        (const __attribute__((address_space(1))) void*)g,
        (__attribute__((address_space(3))) void*)l, 16, 0, 0);
}

// ---------------------------------------------------------------------------
// cast_w: Wq|Wk|Wv fp32 -> Wh fp16 [3][256][256]   (unchanged, verified)
// ---------------------------------------------------------------------------
__global__ __launch_bounds__(256) void cast_w(
    const float* __restrict__ Wq, const float* __restrict__ Wk,
    const float* __restrict__ Wv, _Float16* __restrict__ Wh)
{
    int i = (blockIdx.x * 256 + threadIdx.x) * 4;
    const float* src = (i < 65536) ? (Wq + i)
                     : (i < 131072) ? (Wk + (i - 65536)) : (Wv + (i - 131072));
    float4 v = *(const float4*)src;
    f16x4 h = { (_Float16)v.x, (_Float16)v.y, (_Float16)v.z, (_Float16)v.w };
    *(f16x4*)(Wh + i) = h;
}

// ---------------------------------------------------------------------------
// cast_x: x [B,C,N] fp32 -> Xt [B,N,C] fp16   (unchanged, verified)
// ---------------------------------------------------------------------------
__global__ __launch_bounds__(256) void cast_x(
    const float* __restrict__ x1, const float* __restrict__ x2,
    _Float16* __restrict__ Xt1, _Float16* __restrict__ Xt2)
{
    const int tid = threadIdx.x;
    const int n0 = blockIdx.x * 64;
    const int c0 = blockIdx.y * 64;
    const int bz = blockIdx.z;
    const float* X   = (bz < 8) ? x1 : x2;
    _Float16*   Xt   = (bz < 8) ? Xt1 : Xt2;
    const int b = bz & 7;

    __shared__ _Float16 T[64][72];

    {
        const int cl = tid >> 2, nch = (tid & 3) * 16;
        const float* src = X + (size_t)(b * CDIM + c0 + cl) * NTOK + n0 + nch;
#pragma unroll
        for (int u = 0; u < 4; ++u) {
            float4 v = *(const float4*)(src + u * 4);
            T[cl][nch + u * 4 + 0] = (_Float16)v.x;
            T[cl][nch + u * 4 + 1] = (_Float16)v.y;
            T[cl][nch + u * 4 + 2] = (_Float16)v.z;
            T[cl][nch + u * 4 + 3] = (_Float16)v.w;
        }
    }
    __syncthreads();
    {
        const int nl = tid >> 2, cch = (tid & 3) * 16;
        _Float16* dst = Xt + (size_t)(b * NTOK + n0 + nl) * CDIM + c0 + cch;
        f16x8 o0, o1;
#pragma unroll
        for (int i = 0; i < 8; ++i) {
            o0[i] = T[cch + i][nl];
            o1[i] = T[cch + 8 + i][nl];
        }
        *(f16x8*)dst = o0;
        *(f16x8*)(dst + 8) = o1;
    }
}

// ---------------------------------------------------------------------------
// proj_mfma   (unchanged, verified)
// ---------------------------------------------------------------------------
__global__ __launch_bounds__(256, 2) void proj_mfma(
    const _Float16* __restrict__ Xt1, const _Float16* __restrict__ Xt2,
    const _Float16* __restrict__ Wh,
    const float* __restrict__ bq, const float* __restrict__ bk,
    const float* __restrict__ bv,
    _Float16* __restrict__ Qo, _Float16* __restrict__ Ko, _Float16* __restrict__ Vo)
{
    const int tid  = threadIdx.x;
    const int lane = tid & 63;
    const int w    = tid >> 6;
    const int l15  = lane & 15, l4 = lane >> 4;
    const int n0   = blockIdx.x * 64;
    const int mode = blockIdx.y;
    const int b    = blockIdx.z;

    const _Float16* Xt = (mode == 0) ? Xt1 : Xt2;
    const _Float16* Wm = Wh + mode * 65536;
    const float* bias  = (mode == 0) ? bq : (mode == 1) ? bk : bv;
    _Float16* OUT      = (mode == 0) ? Qo : (mode == 1) ? Ko : Vo;

    __shared__ __align__(16) char sm[65536];
    _Float16* Xl = (_Float16*)sm;
    _Float16* Wl = (_Float16*)(sm + 32768);

#pragma unroll
    for (int t = 0; t < 8; ++t) {
        int i = w * 8 + t;
        int row = 2 * i + (lane >> 5);
        int ch  = lane & 31;
        gl_lds16(Xt + (size_t)(b * NTOK + n0 + row) * CDIM + ((ch ^ (row & 7)) * 8),
                 (char*)Xl + i * 1024);
    }

    float bias_o[4];
#pragma unroll
    for (int ot = 0; ot < 4; ++ot) bias_o[ot] = bias[w * 64 + ot * 16 + l15];

    f32x4 acc[16];
#pragma unroll
    for (int i = 0; i < 16; ++i) acc[i] = (f32x4){0.f, 0.f, 0.f, 0.f};

    for (int c0 = 0; c0 < CDIM; c0 += 64) {
        __syncthreads();
#pragma unroll
        for (int t = 0; t < 8; ++t) {
            int i = w * 8 + t;
            int row = 8 * i + (lane >> 3);
            int ch  = lane & 7;
            gl_lds16(Wm + (size_t)row * CDIM + c0 + ((ch ^ (row & 7)) * 8),
                     (char*)Wl + i * 1024);
        }
        __syncthreads();

#pragma unroll
        for (int kk2 = 0; kk2 < 2; ++kk2) {
            f16x8 a[4], bf[4];
#pragma unroll
            for (int nt = 0; nt < 4; ++nt) {
                int row = nt * 16 + l15;
                int ch  = ((c0 >> 3) + kk2 * 4 + l4) ^ (row & 7);
                a[nt] = *(const f16x8*)((const char*)Xl + row * 512 + ch * 16);
            }
#pragma unroll
            for (int ot = 0; ot < 4; ++ot) {
                int row = w * 64 + ot * 16 + l15;
                int ch  = (kk2 * 4 + l4) ^ (row & 7);
                bf[ot] = *(const f16x8*)((const char*)Wl + row * 128 + ch * 16);
            }
#pragma unroll
            for (int nt = 0; nt < 4; ++nt)
#pragma unroll
                for (int ot = 0; ot < 4; ++ot)
                    acc[nt * 4 + ot] = MFMA16(a[nt], bf[ot], acc[nt * 4 + ot]);
        }
    }

    __syncthreads();

    if (mode <= 1) {
        _Float16* Dl = (_Float16*)sm;
#pragma unroll
        for (int nt = 0; nt < 4; ++nt)
#pragma unroll
            for (int ot = 0; ot < 4; ++ot)
#pragma unroll
                for (int reg = 0; reg < 4; ++reg)
                    Dl[(nt * 16 + 4 * l4 + reg) * 256 + w * 64 + ot * 16 + l15] =
                        (_Float16)(acc[nt * 4 + ot][reg] + bias_o[ot]);
        __syncthreads();
        char* dst = (char*)(OUT + ((size_t)b * NTOK + n0) * CDIM);
#pragma unroll
        for (int u = 0; u < 8; ++u) {
            f16x8 v = *(const f16x8*)((const char*)Dl + u * 4096 + tid * 16);
            *(f16x8*)(dst + u * 4096 + tid * 16) = v;
        }
    } else {
        _Float16* Dlv = (_Float16*)sm;   // [256][80]
#pragma unroll
        for (int nt = 0; nt < 4; ++nt)
#pragma unroll
            for (int ot = 0; ot < 4; ++ot)
#pragma unroll
                for (int reg = 0; reg < 4; ++reg)
                    Dlv[(w * 64 + ot * 16 + l15) * 80 + nt * 16 + 4 * l4 + reg] =
                        (_Float16)(acc[nt * 4 + ot][reg] + bias_o[ot]);
        __syncthreads();
#pragma unroll
        for (int t = 0; t < 8; ++t) {
            int ro = (w * 8 + t) * 8 + (lane >> 3);
            f16x8 v = *(const f16x8*)((const char*)Dlv + ro * 160 + (lane & 7) * 16);
            *(f16x8*)(OUT + ((size_t)b * CDIM + ro) * NTOK + n0 + (lane & 7) * 8) = v;
        }
    }
}

// ---------------------------------------------------------------------------
// Split-KV MFMA flash attention — KVBLK=32, double-buffered, 2 blocks/CU.
// LDS: 2 x {Kl 16KB + Vl 16KB} dbuf + 8 x 1KB wave-private P = 72KB.
// K tile [32 j][256 c] rows 512B, chunk32 ^= row&7 (verified swizzle).
// V tile [256 c][32 j] rows 64B, LINEAR both sides (conflict-free by layout).
// P tile [16 q][32 j] rows 64B, slot = (j>>3)^(r>>2)^(r&3) (2-level XOR).
// Iteration: issue STAGE(t+1 -> buf^1) -> compute buf -> one barrier.
// ---------------------------------------------------------------------------
template <int SEG>
__global__ __launch_bounds__(512, 4) void attn_fa(
    const _Float16* __restrict__ Q, const _Float16* __restrict__ K,
    const _Float16* __restrict__ Vt, _Float16* __restrict__ pacc,
    float2* __restrict__ pml)
{
    const int tid  = threadIdx.x;
    const int lane = tid & 63;
    const int w    = tid >> 6;
    const int l15  = lane & 15, l4 = lane >> 4;

    // bijective XCD-chunked swizzle (grid % 8 == 0)
    const int nb  = 18 * BATCH * SEG, cpx = nb / 8;
    const int bid = blockIdx.x;
    const int swz = (bid & 7) * cpx + (bid >> 3);
    const int x = swz % 18;
    const int b = (swz / 18) & 7;
    const int z = swz / 144;

    const int row0   = x * 128 + w * 16;
    const int jbase  = z * (NTOK / SEG);
    const int NTILES = NTOK / SEG / 32;

    __shared__ __align__(16) char smem[73728];   // 72KB -> 2 blocks/CU
    _Float16* Pw = (_Float16*)(smem + 65536 + w * 1024);

    const size_t kbb = (size_t)b * NTOK;
    const size_t vbb = (size_t)b * CDIM * NTOK;

    // ---- stage one KV tile (32 j) into buffer buf ----
    auto stage = [&](int j0, int buf) {
        char* Klc = smem + buf * 32768;
        char* Vlc = Klc + 16384;
        // K: 16 instrs (2/wave), each 1KB = 2 rows of 512B
#pragma unroll
        for (int t = 0; t < 2; ++t) {
            int i = w * 2 + t;
            int krow = 2 * i + (lane >> 5);
            int chunk = lane & 31;
            gl_lds16(K + (kbb + j0 + krow) * CDIM + ((chunk ^ (krow & 7)) * 8),
                     Klc + i * 1024);
        }
        // V: 16 instrs (2/wave), each 1KB = 16 rows of 64B, linear
#pragma unroll
        for (int t = 0; t < 2; ++t) {
            int i = w * 2 + t;
            int vrow = 16 * i + (lane >> 2);
            int chunk = lane & 3;
            gl_lds16(Vt + vbb + (size_t)vrow * NTOK + j0 + chunk * 8,
                     Vlc + i * 1024);
        }
    };

    // Q fragments: 16 rows x 256 c (nontemporal single-use stream)
    f16x8 qa[8];
    {
        const _Float16* qb = Q + ((size_t)b * NTOK + row0 + l15) * CDIM + l4 * 8;
#pragma unroll
        for (int kk = 0; kk < 8; ++kk)
            qa[kk] = __builtin_nontemporal_load((const f16x8*)(qb + kk * 32));
    }

    f32x4 acc[16];
#pragma unroll
    for (int ct = 0; ct < 16; ++ct) acc[ct] = (f32x4){0.f, 0.f, 0.f, 0.f};
    float m[4] = {-FLT_MAX, -FLT_MAX, -FLT_MAX, -FLT_MAX};
    float l[4] = {0.f, 0.f, 0.f, 0.f};

    // prologue
    stage(jbase, 0);
    __syncthreads();

    for (int jt = 0; jt < NTILES; ++jt) {
        const int cur = jt & 1;

        // issue next tile's loads (in flight across the whole compute phase)
        if (jt + 1 < NTILES) stage(jbase + (jt + 1) * 32, cur ^ 1);

        const char* Klc = (const char*)smem + cur * 32768;
        const char* Vlc = Klc + 16384;

        // ---- QK^T: S[16 i][32 j] ----
        f32x4 s[2];
        __builtin_amdgcn_s_setprio(1);
#pragma unroll
        for (int nt = 0; nt < 2; ++nt) {
            const char* kb = Klc + (nt * 16 + l15) * 512;
            f32x4 sv = (f32x4){0.f, 0.f, 0.f, 0.f};
#pragma unroll
            for (int kk = 0; kk < 8; ++kk) {
                f16x8 kf = *(const f16x8*)(kb + (((kk * 4 + l4) ^ (l15 & 7)) * 16));
                sv = MFMA16(qa[kk], kf, sv);
            }
            s[nt] = sv;
        }
        __builtin_amdgcn_s_setprio(0);

        // ---- online softmax (rows i = 4*l4 + reg), defer-max THR=8 ----
#pragma unroll
        for (int reg = 0; reg < 4; ++reg) {
            float pm = fmaxf(s[0][reg], s[1][reg]);
            pm = fmaxf(pm, __shfl_xor(pm, 1));
            pm = fmaxf(pm, __shfl_xor(pm, 2));
            pm = fmaxf(pm, __shfl_xor(pm, 4));
            pm = fmaxf(pm, __shfl_xor(pm, 8));
            if (pm > m[reg] + 8.f) {
                float sc = __expf(m[reg] - pm);
                m[reg] = pm;
                l[reg] *= sc;
#pragma unroll
                for (int ct = 0; ct < 16; ++ct) acc[ct][reg] *= sc;
            }
            float ps = 0.f;
            const int r = 4 * l4 + reg;
#pragma unroll
            for (int nt = 0; nt < 2; ++nt) {
                float p = __expf(s[nt][reg] - m[reg]);
                ps += p;
                int j = nt * 16 + l15;
                int slot = (j >> 3) ^ l4 ^ reg;     // (j>>3)^(r>>2)^(r&3)
                Pw[r * 32 + slot * 8 + (j & 7)] = (_Float16)p;
            }
            ps += __shfl_xor(ps, 1);
            ps += __shfl_xor(ps, 2);
            ps += __shfl_xor(ps, 4);
            ps += __shfl_xor(ps, 8);
            l[reg] += ps;
        }

        // wave-private P dependency: drain LDS writes, fence scheduler
        asm volatile("s_waitcnt lgkmcnt(0)" ::: "memory");
        __builtin_amdgcn_sched_barrier(0);

        // ---- PV: acc[16 i][256 c] += P[16 i][32 j] * V[32 j][256 c] ----
        f16x8 pa = *(const f16x8*)((const char*)Pw + l15 * 64
                                   + ((l4 ^ (l15 >> 2) ^ (l15 & 3)) * 16));
        __builtin_amdgcn_s_setprio(1);
#pragma unroll
        for (int ct = 0; ct < 16; ++ct) {
            f16x8 vb = *(const f16x8*)(Vlc + (ct * 16 + l15) * 64 + l4 * 16);
            acc[ct] = MFMA16(pa, vb, acc[ct]);
        }
        __builtin_amdgcn_s_setprio(0);

        // drain own staging loads + barrier: next buffer landed, cur released
        __syncthreads();
    }

    // ---- epilogue: LDS-staged, plain linear 16B/lane pacc stores ----
    _Float16* stg = (_Float16*)(smem + w * 8192);
#pragma unroll
    for (int reg = 0; reg < 4; ++reg) {
        float inv = 1.f / l[reg];
        int r = 4 * l4 + reg;
#pragma unroll
        for (int ct = 0; ct < 16; ++ct)
            stg[r * 256 + ct * 16 + l15] = (_Float16)(acc[ct][reg] * inv);
        if (l15 == 0)
            pml[((size_t)z * BATCH + b) * NTOK + row0 + r] = make_float2(m[reg], l[reg]);
    }
    asm volatile("s_waitcnt lgkmcnt(0)" ::: "memory");
    __builtin_amdgcn_sched_barrier(0);
    {
        const char* stgc = (const char*)stg;
        char* dst = (char*)(pacc + ((size_t)z * BATCH + b) * NTOK * CDIM
                            + (size_t)row0 * CDIM);
#pragma unroll
        for (int u = 0; u < 8; ++u) {
            f16x8 v = *(const f16x8*)(stgc + u * 1024 + lane * 16);
            *(f16x8*)(dst + u * 1024 + lane * 16) = v;
        }
    }
}

// ---------------------------------------------------------------------------
// Merge (unchanged, verified)
// ---------------------------------------------------------------------------
template <int SEG>
__global__ __launch_bounds__(256) void merge_kernel(
    const _Float16* __restrict__ pacc, const float2* __restrict__ pml,
    float* __restrict__ out)
{
    const int tid = threadIdx.x;
    const int n0 = blockIdx.x * 64;
    const int b  = blockIdx.y;

    __shared__ float wgt[SEG][64];
    __shared__ float dinv[64];
    __shared__ float T[64][68];

    if (tid < 64) {
        int n = n0 + tid;
        float ms[SEG], ls[SEG];
#pragma unroll
        for (int s = 0; s < SEG; ++s) {
            float2 v = pml[((size_t)s * BATCH + b) * NTOK + n];
            ms[s] = v.x; ls[s] = v.y;
        }
        float M = ms[0];
#pragma unroll
        for (int s = 1; s < SEG; ++s) M = fmaxf(M, ms[s]);
        float den = 0.f;
#pragma unroll
        for (int s = 0; s < SEG; ++s) {
            float g = ls[s] * __expf(ms[s] - M);
            wgt[s][tid] = g;
            den += g;
        }
        dinv[tid] = 1.f / den;
    }
    __syncthreads();

    for (int cc = 0; cc < 4; ++cc) {
        const int nl = tid >> 2, cg = (tid & 3) * 16;
        float a[16];
#pragma unroll
        for (int u = 0; u < 16; ++u) a[u] = 0.f;
#pragma unroll
        for (int s = 0; s < SEG; ++s) {
            const _Float16* p = pacc + (((size_t)s * BATCH + b) * NTOK + n0 + nl) * CDIM
                                + cc * 64 + cg;
            f16x8 v0 = ((const f16x8*)p)[0];
            f16x8 v1 = ((const f16x8*)p)[1];
            float g = wgt[s][nl];
#pragma unroll
            for (int u = 0; u < 8; ++u) {
                a[u]     += g * (float)v0[u];
                a[8 + u] += g * (float)v1[u];
            }
        }
        float di = dinv[nl];
#pragma unroll
        for (int u = 0; u < 16; ++u) T[nl][cg + u] = a[u] * di;
        __syncthreads();

        const int cl = tid >> 2, nb2 = (tid & 3) * 16;
        float* ob = out + ((size_t)b * CDIM + cc * 64 + cl) * NTOK + n0 + nb2;
#pragma unroll
        for (int u = 0; u < 4; ++u) {
            float4 v = { T[nb2 + u * 4 + 0][cl], T[nb2 + u * 4 + 1][cl],
                         T[nb2 + u * 4 + 2][cl], T[nb2 + u * 4 + 3][cl] };
            *(float4*)&ob[u * 4] = v;
        }
        __syncthreads();
    }
}

// ---------------------------------------------------------------------------
extern "C" void kernel_launch(void* const* d_in, const int* in_sizes, int n_in,
                              void* d_out, int out_size, void* d_ws, size_t ws_size,
                              hipStream_t stream)
{
    const float* x1 = (const float*)d_in[0];
    const float* x2 = (const float*)d_in[1];
    const float* Wq = (const float*)d_in[2];
    const float* bq = (const float*)d_in[3];
    const float* Wk = (const float*)d_in[4];
    const float* bk = (const float*)d_in[5];
    const float* Wv = (const float*)d_in[6];
    const float* bv = (const float*)d_in[7];
    float* out = (float*)d_out;

    const size_t plane = (size_t)BATCH * NTOK * CDIM;   // 4,718,592
    _Float16* ws16 = (_Float16*)d_ws;
    _Float16* Q   = ws16;
    _Float16* K   = ws16 + plane;
    _Float16* Vt  = ws16 + 2 * plane;
    _Float16* Xt1 = ws16 + 3 * plane;
    _Float16* Xt2 = ws16 + 4 * plane;
    _Float16* Wh  = ws16 + 5 * plane;
    const size_t fixed16 = 5 * plane + 196608;

    auto need = [&](size_t S) {
        return fixed16 * 2 + S * plane * 2 + S * (size_t)BATCH * NTOK * 8;
    };
    const int SEG = (ws_size >= need(4)) ? 4 : (ws_size >= need(2)) ? 2 : 1;

    _Float16* pacc = ws16 + fixed16;
    float2*   pml  = (float2*)((char*)d_ws + fixed16 * 2 + (size_t)SEG * plane * 2);

    cast_w<<<dim3(192), dim3(256), 0, stream>>>(Wq, Wk, Wv, Wh);
    cast_x<<<dim3(36, 4, 16), dim3(256), 0, stream>>>(x1, x2, Xt1, Xt2);
    proj_mfma<<<dim3(36, 3, BATCH), dim3(256), 0, stream>>>(
        Xt1, Xt2, Wh, bq, bk, bv, Q, K, Vt);

    const int nb = 18 * BATCH;
    if (SEG == 4) {
        attn_fa<4><<<dim3(nb * 4), dim3(512), 0, stream>>>(Q, K, Vt, pacc, pml);
        merge_kernel<4><<<dim3(36, BATCH), dim3(256), 0, stream>>>(pacc, pml, out);
    } else if (SEG == 2) {
        attn_fa<2><<<dim3(nb * 2), dim3(512), 0, stream>>>(Q, K, Vt, pacc, pml);
        merge_kernel<2><<<dim3(36, BATCH), dim3(256), 0, stream>>>(pacc, pml, out);
    } else {
        attn_fa<1><<<dim3(nb), dim3(512), 0, stream>>>(Q, K, Vt, pacc, pml);
        merge_kernel<1><<<dim3(36, BATCH), dim3(256), 0, stream>>>(pacc, pml, out);
    }
}

// Round 8
// 186.148 us; speedup vs baseline: 2.2637x; 2.2637x over previous
//
#include <hip/hip_runtime.h>
#include <cfloat>
#include <cstddef>
#include <cstdint>

#define BATCH 8
#define CDIM  256
#define NTOK  2304   // 48*48

typedef float    f32x4 __attribute__((ext_vector_type(4)));
typedef _Float16 f16x8 __attribute__((ext_vector_type(8)));
typedef _Float16 f16x4 __attribute__((ext_vector_type(4)));

#define MFMA16(a, b, c) __builtin_amdgcn_mfma_f32_16x16x32_f16(a, b, c, 0, 0, 0)

__device__ __forceinline__ void gl_lds16(const void* g, void* l) {
    __builtin_amdgcn_global_load_lds(
        (const __attribute__((address_space(1))) void*)g,
        (__attribute__((address_space(3))) void*)l, 16, 0, 0);
}

// ---------------------------------------------------------------------------
// cast_w: Wq|Wk|Wv fp32 -> Wh fp16 [3][256][256]   (unchanged, verified)
// ---------------------------------------------------------------------------
__global__ __launch_bounds__(256) void cast_w(
    const float* __restrict__ Wq, const float* __restrict__ Wk,
    const float* __restrict__ Wv, _Float16* __restrict__ Wh)
{
    int i = (blockIdx.x * 256 + threadIdx.x) * 4;
    const float* src = (i < 65536) ? (Wq + i)
                     : (i < 131072) ? (Wk + (i - 65536)) : (Wv + (i - 131072));
    float4 v = *(const float4*)src;
    f16x4 h = { (_Float16)v.x, (_Float16)v.y, (_Float16)v.z, (_Float16)v.w };
    *(f16x4*)(Wh + i) = h;
}

// ---------------------------------------------------------------------------
// cast_x: x [B,C,N] fp32 -> Xt [B,N,C] fp16   (unchanged, verified)
// ---------------------------------------------------------------------------
__global__ __launch_bounds__(256) void cast_x(
    const float* __restrict__ x1, const float* __restrict__ x2,
    _Float16* __restrict__ Xt1, _Float16* __restrict__ Xt2)
{
    const int tid = threadIdx.x;
    const int n0 = blockIdx.x * 64;
    const int c0 = blockIdx.y * 64;
    const int bz = blockIdx.z;
    const float* X   = (bz < 8) ? x1 : x2;
    _Float16*   Xt   = (bz < 8) ? Xt1 : Xt2;
    const int b = bz & 7;

    __shared__ _Float16 T[64][72];

    {
        const int cl = tid >> 2, nch = (tid & 3) * 16;
        const float* src = X + (size_t)(b * CDIM + c0 + cl) * NTOK + n0 + nch;
#pragma unroll
        for (int u = 0; u < 4; ++u) {
            float4 v = *(const float4*)(src + u * 4);
            T[cl][nch + u * 4 + 0] = (_Float16)v.x;
            T[cl][nch + u * 4 + 1] = (_Float16)v.y;
            T[cl][nch + u * 4 + 2] = (_Float16)v.z;
            T[cl][nch + u * 4 + 3] = (_Float16)v.w;
        }
    }
    __syncthreads();
    {
        const int nl = tid >> 2, cch = (tid & 3) * 16;
        _Float16* dst = Xt + (size_t)(b * NTOK + n0 + nl) * CDIM + c0 + cch;
        f16x8 o0, o1;
#pragma unroll
        for (int i = 0; i < 8; ++i) {
            o0[i] = T[cch + i][nl];
            o1[i] = T[cch + 8 + i][nl];
        }
        *(f16x8*)dst = o0;
        *(f16x8*)(dst + 8) = o1;
    }
}

// ---------------------------------------------------------------------------
// proj_mfma   (unchanged, verified)
// ---------------------------------------------------------------------------
__global__ __launch_bounds__(256, 2) void proj_mfma(
    const _Float16* __restrict__ Xt1, const _Float16* __restrict__ Xt2,
    const _Float16* __restrict__ Wh,
    const float* __restrict__ bq, const float* __restrict__ bk,
    const float* __restrict__ bv,
    _Float16* __restrict__ Qo, _Float16* __restrict__ Ko, _Float16* __restrict__ Vo)
{
    const int tid  = threadIdx.x;
    const int lane = tid & 63;
    const int w    = tid >> 6;
    const int l15  = lane & 15, l4 = lane >> 4;
    const int n0   = blockIdx.x * 64;
    const int mode = blockIdx.y;
    const int b    = blockIdx.z;

    const _Float16* Xt = (mode == 0) ? Xt1 : Xt2;
    const _Float16* Wm = Wh + mode * 65536;
    const float* bias  = (mode == 0) ? bq : (mode == 1) ? bk : bv;
    _Float16* OUT      = (mode == 0) ? Qo : (mode == 1) ? Ko : Vo;

    __shared__ __align__(16) char sm[65536];
    _Float16* Xl = (_Float16*)sm;
    _Float16* Wl = (_Float16*)(sm + 32768);

#pragma unroll
    for (int t = 0; t < 8; ++t) {
        int i = w * 8 + t;
        int row = 2 * i + (lane >> 5);
        int ch  = lane & 31;
        gl_lds16(Xt + (size_t)(b * NTOK + n0 + row) * CDIM + ((ch ^ (row & 7)) * 8),
                 (char*)Xl + i * 1024);
    }

    float bias_o[4];
#pragma unroll
    for (int ot = 0; ot < 4; ++ot) bias_o[ot] = bias[w * 64 + ot * 16 + l15];

    f32x4 acc[16];
#pragma unroll
    for (int i = 0; i < 16; ++i) acc[i] = (f32x4){0.f, 0.f, 0.f, 0.f};

    for (int c0 = 0; c0 < CDIM; c0 += 64) {
        __syncthreads();
#pragma unroll
        for (int t = 0; t < 8; ++t) {
            int i = w * 8 + t;
            int row = 8 * i + (lane >> 3);
            int ch  = lane & 7;
            gl_lds16(Wm + (size_t)row * CDIM + c0 + ((ch ^ (row & 7)) * 8),
                     (char*)Wl + i * 1024);
        }
        __syncthreads();

#pragma unroll
        for (int kk2 = 0; kk2 < 2; ++kk2) {
            f16x8 a[4], bf[4];
#pragma unroll
            for (int nt = 0; nt < 4; ++nt) {
                int row = nt * 16 + l15;
                int ch  = ((c0 >> 3) + kk2 * 4 + l4) ^ (row & 7);
                a[nt] = *(const f16x8*)((const char*)Xl + row * 512 + ch * 16);
            }
#pragma unroll
            for (int ot = 0; ot < 4; ++ot) {
                int row = w * 64 + ot * 16 + l15;
                int ch  = (kk2 * 4 + l4) ^ (row & 7);
                bf[ot] = *(const f16x8*)((const char*)Wl + row * 128 + ch * 16);
            }
#pragma unroll
            for (int nt = 0; nt < 4; ++nt)
#pragma unroll
                for (int ot = 0; ot < 4; ++ot)
                    acc[nt * 4 + ot] = MFMA16(a[nt], bf[ot], acc[nt * 4 + ot]);
        }
    }

    __syncthreads();

    if (mode <= 1) {
        _Float16* Dl = (_Float16*)sm;
#pragma unroll
        for (int nt = 0; nt < 4; ++nt)
#pragma unroll
            for (int ot = 0; ot < 4; ++ot)
#pragma unroll
                for (int reg = 0; reg < 4; ++reg)
                    Dl[(nt * 16 + 4 * l4 + reg) * 256 + w * 64 + ot * 16 + l15] =
                        (_Float16)(acc[nt * 4 + ot][reg] + bias_o[ot]);
        __syncthreads();
        char* dst = (char*)(OUT + ((size_t)b * NTOK + n0) * CDIM);
#pragma unroll
        for (int u = 0; u < 8; ++u) {
            f16x8 v = *(const f16x8*)((const char*)Dl + u * 4096 + tid * 16);
            *(f16x8*)(dst + u * 4096 + tid * 16) = v;
        }
    } else {
        _Float16* Dlv = (_Float16*)sm;   // [256][80]
#pragma unroll
        for (int nt = 0; nt < 4; ++nt)
#pragma unroll
            for (int ot = 0; ot < 4; ++ot)
#pragma unroll
                for (int reg = 0; reg < 4; ++reg)
                    Dlv[(w * 64 + ot * 16 + l15) * 80 + nt * 16 + 4 * l4 + reg] =
                        (_Float16)(acc[nt * 4 + ot][reg] + bias_o[ot]);
        __syncthreads();
#pragma unroll
        for (int t = 0; t < 8; ++t) {
            int ro = (w * 8 + t) * 8 + (lane >> 3);
            f16x8 v = *(const f16x8*)((const char*)Dlv + ro * 160 + (lane & 7) * 16);
            *(f16x8*)(OUT + ((size_t)b * CDIM + ro) * NTOK + n0 + (lane & 7) * 8) = v;
        }
    }
}

// ---------------------------------------------------------------------------
// Split-KV MFMA flash attention — KVBLK=32, double-buffered, 72KB LDS.
// FIXES vs round 7:
//  * __launch_bounds__(512, 2): full 256-reg budget (r7's (512,4) halved it
//    to 64 arch VGPRs -> scratch spills -> 628MB FETCH). Actual use ~112
//    still allows 16 waves/CU; LDS 72KB -> 2 blocks/CU.
//  * V tile pair-interleaved + XOR swizzle (both-sides involution):
//    LDS row = c-pair (128B): slot8 = ((c&1)*4 + jc) ^ (cpair&7).
//    r7's linear V read was an 8-way bank conflict (rows 64B = 0 mod 128B).
// K tile [32 j][256 c] rows 512B, chunk32 ^= row&7 (verified).
// P tile [16 q][32 j], slot = (j>>3)^(r>>2)^(r&3) (verified r7, correct).
// ---------------------------------------------------------------------------
template <int SEG>
__global__ __launch_bounds__(512, 2) void attn_fa(
    const _Float16* __restrict__ Q, const _Float16* __restrict__ K,
    const _Float16* __restrict__ Vt, _Float16* __restrict__ pacc,
    float2* __restrict__ pml)
{
    const int tid  = threadIdx.x;
    const int lane = tid & 63;
    const int w    = tid >> 6;
    const int l15  = lane & 15, l4 = lane >> 4;

    // bijective XCD-chunked swizzle (grid % 8 == 0)
    const int nb  = 18 * BATCH * SEG, cpx = nb / 8;
    const int bid = blockIdx.x;
    const int swz = (bid & 7) * cpx + (bid >> 3);
    const int x = swz % 18;
    const int b = (swz / 18) & 7;
    const int z = swz / 144;

    const int row0   = x * 128 + w * 16;
    const int jbase  = z * (NTOK / SEG);
    const int NTILES = NTOK / SEG / 32;

    __shared__ __align__(16) char smem[73728];   // 72KB -> 2 blocks/CU
    _Float16* Pw = (_Float16*)(smem + 65536 + w * 1024);

    const size_t kbb = (size_t)b * NTOK;
    const size_t vbb = (size_t)b * CDIM * NTOK;

    // ---- stage one KV tile (32 j) into buffer buf ----
    auto stage = [&](int j0, int buf) {
        char* Klc = smem + buf * 32768;
        char* Vlc = Klc + 16384;
        // K: 16 instrs (2/wave), each 1KB = 2 rows of 512B, chunk^row&7
#pragma unroll
        for (int t = 0; t < 2; ++t) {
            int i = w * 2 + t;
            int krow = 2 * i + (lane >> 5);
            int chunk = lane & 31;
            gl_lds16(K + (kbb + j0 + krow) * CDIM + ((chunk ^ (krow & 7)) * 8),
                     Klc + i * 1024);
        }
        // V: 16 instrs (2/wave), each 1KB = 8 c-pairs of 128B.
        // slot involution: staged (codd,jc) at slot = (codd*4+jc)^(cpair&7)
#pragma unroll
        for (int t = 0; t < 2; ++t) {
            int i = w * 2 + t;
            int cpair = i * 8 + (lane >> 3);
            int val   = (lane & 7) ^ (cpair & 7);
            int codd  = val >> 2, jc = val & 3;
            gl_lds16(Vt + vbb + (size_t)(2 * cpair + codd) * NTOK + j0 + jc * 8,
                     Vlc + i * 1024);
        }
    };

    // Q fragments: 16 rows x 256 c (nontemporal single-use stream)
    f16x8 qa[8];
    {
        const _Float16* qb = Q + ((size_t)b * NTOK + row0 + l15) * CDIM + l4 * 8;
#pragma unroll
        for (int kk = 0; kk < 8; ++kk)
            qa[kk] = __builtin_nontemporal_load((const f16x8*)(qb + kk * 32));
    }

    f32x4 acc[16];
#pragma unroll
    for (int ct = 0; ct < 16; ++ct) acc[ct] = (f32x4){0.f, 0.f, 0.f, 0.f};
    float m[4] = {-FLT_MAX, -FLT_MAX, -FLT_MAX, -FLT_MAX};
    float l[4] = {0.f, 0.f, 0.f, 0.f};

    // prologue
    stage(jbase, 0);
    __syncthreads();

    for (int jt = 0; jt < NTILES; ++jt) {
        const int cur = jt & 1;

        // issue next tile's loads (in flight across the whole compute phase)
        if (jt + 1 < NTILES) stage(jbase + (jt + 1) * 32, cur ^ 1);

        const char* Klc = (const char*)smem + cur * 32768;
        const char* Vlc = Klc + 16384;

        // ---- QK^T: S[16 i][32 j] ----
        f32x4 s[2];
        __builtin_amdgcn_s_setprio(1);
#pragma unroll
        for (int nt = 0; nt < 2; ++nt) {
            const char* kb = Klc + (nt * 16 + l15) * 512;
            f32x4 sv = (f32x4){0.f, 0.f, 0.f, 0.f};
#pragma unroll
            for (int kk = 0; kk < 8; ++kk) {
                f16x8 kf = *(const f16x8*)(kb + (((kk * 4 + l4) ^ (l15 & 7)) * 16));
                sv = MFMA16(qa[kk], kf, sv);
            }
            s[nt] = sv;
        }
        __builtin_amdgcn_s_setprio(0);

        // ---- online softmax (rows i = 4*l4 + reg), defer-max THR=8 ----
#pragma unroll
        for (int reg = 0; reg < 4; ++reg) {
            float pm = fmaxf(s[0][reg], s[1][reg]);
            pm = fmaxf(pm, __shfl_xor(pm, 1));
            pm = fmaxf(pm, __shfl_xor(pm, 2));
            pm = fmaxf(pm, __shfl_xor(pm, 4));
            pm = fmaxf(pm, __shfl_xor(pm, 8));
            if (pm > m[reg] + 8.f) {
                float sc = __expf(m[reg] - pm);
                m[reg] = pm;
                l[reg] *= sc;
#pragma unroll
                for (int ct = 0; ct < 16; ++ct) acc[ct][reg] *= sc;
            }
            float ps = 0.f;
            const int r = 4 * l4 + reg;
#pragma unroll
            for (int nt = 0; nt < 2; ++nt) {
                float p = __expf(s[nt][reg] - m[reg]);
                ps += p;
                int j = nt * 16 + l15;
                int slot = (j >> 3) ^ l4 ^ reg;     // (j>>3)^(r>>2)^(r&3)
                Pw[r * 32 + slot * 8 + (j & 7)] = (_Float16)p;
            }
            ps += __shfl_xor(ps, 1);
            ps += __shfl_xor(ps, 2);
            ps += __shfl_xor(ps, 4);
            ps += __shfl_xor(ps, 8);
            l[reg] += ps;
        }

        // wave-private P dependency: drain LDS writes, fence scheduler
        asm volatile("s_waitcnt lgkmcnt(0)" ::: "memory");
        __builtin_amdgcn_sched_barrier(0);

        // ---- PV: acc[16 i][256 c] += P[16 i][32 j] * V[32 j][256 c] ----
        f16x8 pa = *(const f16x8*)((const char*)Pw + l15 * 64
                                   + ((l4 ^ (l15 >> 2) ^ (l15 & 3)) * 16));
        __builtin_amdgcn_s_setprio(1);
#pragma unroll
        for (int ct = 0; ct < 16; ++ct) {
            int cpair = (ct * 16 + l15) >> 1;              // 8ct + (l15>>1)
            int slot  = (((l15 & 1) * 4 + l4) ^ ((l15 >> 1) & 7));
            f16x8 vb = *(const f16x8*)(Vlc + cpair * 128 + slot * 16);
            acc[ct] = MFMA16(pa, vb, acc[ct]);
        }
        __builtin_amdgcn_s_setprio(0);

        // drain own staging loads + barrier: next buffer landed, cur released
        __syncthreads();
    }

    // ---- epilogue: LDS-staged, plain linear 16B/lane pacc stores ----
    _Float16* stg = (_Float16*)(smem + w * 8192);
#pragma unroll
    for (int reg = 0; reg < 4; ++reg) {
        float inv = 1.f / l[reg];
        int r = 4 * l4 + reg;
#pragma unroll
        for (int ct = 0; ct < 16; ++ct)
            stg[r * 256 + ct * 16 + l15] = (_Float16)(acc[ct][reg] * inv);
        if (l15 == 0)
            pml[((size_t)z * BATCH + b) * NTOK + row0 + r] = make_float2(m[reg], l[reg]);
    }
    asm volatile("s_waitcnt lgkmcnt(0)" ::: "memory");
    __builtin_amdgcn_sched_barrier(0);
    {
        const char* stgc = (const char*)stg;
        char* dst = (char*)(pacc + ((size_t)z * BATCH + b) * NTOK * CDIM
                            + (size_t)row0 * CDIM);
#pragma unroll
        for (int u = 0; u < 8; ++u) {
            f16x8 v = *(const f16x8*)(stgc + u * 1024 + lane * 16);
            *(f16x8*)(dst + u * 1024 + lane * 16) = v;
        }
    }
}

// ---------------------------------------------------------------------------
// Merge (unchanged, verified)
// ---------------------------------------------------------------------------
template <int SEG>
__global__ __launch_bounds__(256) void merge_kernel(
    const _Float16* __restrict__ pacc, const float2* __restrict__ pml,
    float* __restrict__ out)
{
    const int tid = threadIdx.x;
    const int n0 = blockIdx.x * 64;
    const int b  = blockIdx.y;

    __shared__ float wgt[SEG][64];
    __shared__ float dinv[64];
    __shared__ float T[64][68];

    if (tid < 64) {
        int n = n0 + tid;
        float ms[SEG], ls[SEG];
#pragma unroll
        for (int s = 0; s < SEG; ++s) {
            float2 v = pml[((size_t)s * BATCH + b) * NTOK + n];
            ms[s] = v.x; ls[s] = v.y;
        }
        float M = ms[0];
#pragma unroll
        for (int s = 1; s < SEG; ++s) M = fmaxf(M, ms[s]);
        float den = 0.f;
#pragma unroll
        for (int s = 0; s < SEG; ++s) {
            float g = ls[s] * __expf(ms[s] - M);
            wgt[s][tid] = g;
            den += g;
        }
        dinv[tid] = 1.f / den;
    }
    __syncthreads();

    for (int cc = 0; cc < 4; ++cc) {
        const int nl = tid >> 2, cg = (tid & 3) * 16;
        float a[16];
#pragma unroll
        for (int u = 0; u < 16; ++u) a[u] = 0.f;
#pragma unroll
        for (int s = 0; s < SEG; ++s) {
            const _Float16* p = pacc + (((size_t)s * BATCH + b) * NTOK + n0 + nl) * CDIM
                                + cc * 64 + cg;
            f16x8 v0 = ((const f16x8*)p)[0];
            f16x8 v1 = ((const f16x8*)p)[1];
            float g = wgt[s][nl];
#pragma unroll
            for (int u = 0; u < 8; ++u) {
                a[u]     += g * (float)v0[u];
                a[8 + u] += g * (float)v1[u];
            }
        }
        float di = dinv[nl];
#pragma unroll
        for (int u = 0; u < 16; ++u) T[nl][cg + u] = a[u] * di;
        __syncthreads();

        const int cl = tid >> 2, nb2 = (tid & 3) * 16;
        float* ob = out + ((size_t)b * CDIM + cc * 64 + cl) * NTOK + n0 + nb2;
#pragma unroll
        for (int u = 0; u < 4; ++u) {
            float4 v = { T[nb2 + u * 4 + 0][cl], T[nb2 + u * 4 + 1][cl],
                         T[nb2 + u * 4 + 2][cl], T[nb2 + u * 4 + 3][cl] };
            *(float4*)&ob[u * 4] = v;
        }
        __syncthreads();
    }
}

// ---------------------------------------------------------------------------
extern "C" void kernel_launch(void* const* d_in, const int* in_sizes, int n_in,
                              void* d_out, int out_size, void* d_ws, size_t ws_size,
                              hipStream_t stream)
{
    const float* x1 = (const float*)d_in[0];
    const float* x2 = (const float*)d_in[1];
    const float* Wq = (const float*)d_in[2];
    const float* bq = (const float*)d_in[3];
    const float* Wk = (const float*)d_in[4];
    const float* bk = (const float*)d_in[5];
    const float* Wv = (const float*)d_in[6];
    const float* bv = (const float*)d_in[7];
    float* out = (float*)d_out;

    const size_t plane = (size_t)BATCH * NTOK * CDIM;   // 4,718,592
    _Float16* ws16 = (_Float16*)d_ws;
    _Float16* Q   = ws16;
    _Float16* K   = ws16 + plane;
    _Float16* Vt  = ws16 + 2 * plane;
    _Float16* Xt1 = ws16 + 3 * plane;
    _Float16* Xt2 = ws16 + 4 * plane;
    _Float16* Wh  = ws16 + 5 * plane;
    const size_t fixed16 = 5 * plane + 196608;

    auto need = [&](size_t S) {
        return fixed16 * 2 + S * plane * 2 + S * (size_t)BATCH * NTOK * 8;
    };
    const int SEG = (ws_size >= need(4)) ? 4 : (ws_size >= need(2)) ? 2 : 1;

    _Float16* pacc = ws16 + fixed16;
    float2*   pml  = (float2*)((char*)d_ws + fixed16 * 2 + (size_t)SEG * plane * 2);

    cast_w<<<dim3(192), dim3(256), 0, stream>>>(Wq, Wk, Wv, Wh);
    cast_x<<<dim3(36, 4, 16), dim3(256), 0, stream>>>(x1, x2, Xt1, Xt2);
    proj_mfma<<<dim3(36, 3, BATCH), dim3(256), 0, stream>>>(
        Xt1, Xt2, Wh, bq, bk, bv, Q, K, Vt);

    const int nb = 18 * BATCH;
    if (SEG == 4) {
        attn_fa<4><<<dim3(nb * 4), dim3(512), 0, stream>>>(Q, K, Vt, pacc, pml);
        merge_kernel<4><<<dim3(36, BATCH), dim3(256), 0, stream>>>(pacc, pml, out);
    } else if (SEG == 2) {
        attn_fa<2><<<dim3(nb * 2), dim3(512), 0, stream>>>(Q, K, Vt, pacc, pml);
        merge_kernel<2><<<dim3(36, BATCH), dim3(256), 0, stream>>>(pacc, pml, out);
    } else {
        attn_fa<1><<<dim3(nb), dim3(512), 0, stream>>>(Q, K, Vt, pacc, pml);
        merge_kernel<1><<<dim3(36, BATCH), dim3(256), 0, stream>>>(pacc, pml, out);
    }
}

// Round 9
// 133.673 us; speedup vs baseline: 3.1524x; 1.3926x over previous
//
#include <hip/hip_runtime.h>
#include <cfloat>
#include <cstddef>
#include <cstdint>

#define BATCH 8
#define CDIM  256
#define NTOK  2304   // 48*48

typedef float    f32x4 __attribute__((ext_vector_type(4)));
typedef _Float16 f16x8 __attribute__((ext_vector_type(8)));
typedef _Float16 f16x4 __attribute__((ext_vector_type(4)));

#define MFMA16(a, b, c) __builtin_amdgcn_mfma_f32_16x16x32_f16(a, b, c, 0, 0, 0)

__device__ __forceinline__ void gl_lds16(const void* g, void* l) {
    __builtin_amdgcn_global_load_lds(
        (const __attribute__((address_space(1))) void*)g,
        (__attribute__((address_space(3))) void*)l, 16, 0, 0);
}

// ---------------------------------------------------------------------------
// cast_w: Wq|Wk|Wv fp32 -> Wh fp16 [3][256][256]   (unchanged, verified)
// ---------------------------------------------------------------------------
__global__ __launch_bounds__(256) void cast_w(
    const float* __restrict__ Wq, const float* __restrict__ Wk,
    const float* __restrict__ Wv, _Float16* __restrict__ Wh)
{
    int i = (blockIdx.x * 256 + threadIdx.x) * 4;
    const float* src = (i < 65536) ? (Wq + i)
                     : (i < 131072) ? (Wk + (i - 65536)) : (Wv + (i - 131072));
    float4 v = *(const float4*)src;
    f16x4 h = { (_Float16)v.x, (_Float16)v.y, (_Float16)v.z, (_Float16)v.w };
    *(f16x4*)(Wh + i) = h;
}

// ---------------------------------------------------------------------------
// cast_x: x [B,C,N] fp32 -> Xt [B,N,C] fp16   (unchanged, verified)
// ---------------------------------------------------------------------------
__global__ __launch_bounds__(256) void cast_x(
    const float* __restrict__ x1, const float* __restrict__ x2,
    _Float16* __restrict__ Xt1, _Float16* __restrict__ Xt2)
{
    const int tid = threadIdx.x;
    const int n0 = blockIdx.x * 64;
    const int c0 = blockIdx.y * 64;
    const int bz = blockIdx.z;
    const float* X   = (bz < 8) ? x1 : x2;
    _Float16*   Xt   = (bz < 8) ? Xt1 : Xt2;
    const int b = bz & 7;

    __shared__ _Float16 T[64][72];

    {
        const int cl = tid >> 2, nch = (tid & 3) * 16;
        const float* src = X + (size_t)(b * CDIM + c0 + cl) * NTOK + n0 + nch;
#pragma unroll
        for (int u = 0; u < 4; ++u) {
            float4 v = *(const float4*)(src + u * 4);
            T[cl][nch + u * 4 + 0] = (_Float16)v.x;
            T[cl][nch + u * 4 + 1] = (_Float16)v.y;
            T[cl][nch + u * 4 + 2] = (_Float16)v.z;
            T[cl][nch + u * 4 + 3] = (_Float16)v.w;
        }
    }
    __syncthreads();
    {
        const int nl = tid >> 2, cch = (tid & 3) * 16;
        _Float16* dst = Xt + (size_t)(b * NTOK + n0 + nl) * CDIM + c0 + cch;
        f16x8 o0, o1;
#pragma unroll
        for (int i = 0; i < 8; ++i) {
            o0[i] = T[cch + i][nl];
            o1[i] = T[cch + 8 + i][nl];
        }
        *(f16x8*)dst = o0;
        *(f16x8*)(dst + 8) = o1;
    }
}

// ---------------------------------------------------------------------------
// proj_mfma   (unchanged, verified)
// ---------------------------------------------------------------------------
__global__ __launch_bounds__(256, 2) void proj_mfma(
    const _Float16* __restrict__ Xt1, const _Float16* __restrict__ Xt2,
    const _Float16* __restrict__ Wh,
    const float* __restrict__ bq, const float* __restrict__ bk,
    const float* __restrict__ bv,
    _Float16* __restrict__ Qo, _Float16* __restrict__ Ko, _Float16* __restrict__ Vo)
{
    const int tid  = threadIdx.x;
    const int lane = tid & 63;
    const int w    = tid >> 6;
    const int l15  = lane & 15, l4 = lane >> 4;
    const int n0   = blockIdx.x * 64;
    const int mode = blockIdx.y;
    const int b    = blockIdx.z;

    const _Float16* Xt = (mode == 0) ? Xt1 : Xt2;
    const _Float16* Wm = Wh + mode * 65536;
    const float* bias  = (mode == 0) ? bq : (mode == 1) ? bk : bv;
    _Float16* OUT      = (mode == 0) ? Qo : (mode == 1) ? Ko : Vo;

    __shared__ __align__(16) char sm[65536];
    _Float16* Xl = (_Float16*)sm;
    _Float16* Wl = (_Float16*)(sm + 32768);

#pragma unroll
    for (int t = 0; t < 8; ++t) {
        int i = w * 8 + t;
        int row = 2 * i + (lane >> 5);
        int ch  = lane & 31;
        gl_lds16(Xt + (size_t)(b * NTOK + n0 + row) * CDIM + ((ch ^ (row & 7)) * 8),
                 (char*)Xl + i * 1024);
    }

    float bias_o[4];
#pragma unroll
    for (int ot = 0; ot < 4; ++ot) bias_o[ot] = bias[w * 64 + ot * 16 + l15];

    f32x4 acc[16];
#pragma unroll
    for (int i = 0; i < 16; ++i) acc[i] = (f32x4){0.f, 0.f, 0.f, 0.f};

    for (int c0 = 0; c0 < CDIM; c0 += 64) {
        __syncthreads();
#pragma unroll
        for (int t = 0; t < 8; ++t) {
            int i = w * 8 + t;
            int row = 8 * i + (lane >> 3);
            int ch  = lane & 7;
            gl_lds16(Wm + (size_t)row * CDIM + c0 + ((ch ^ (row & 7)) * 8),
                     (char*)Wl + i * 1024);
        }
        __syncthreads();

#pragma unroll
        for (int kk2 = 0; kk2 < 2; ++kk2) {
            f16x8 a[4], bf[4];
#pragma unroll
            for (int nt = 0; nt < 4; ++nt) {
                int row = nt * 16 + l15;
                int ch  = ((c0 >> 3) + kk2 * 4 + l4) ^ (row & 7);
                a[nt] = *(const f16x8*)((const char*)Xl + row * 512 + ch * 16);
            }
#pragma unroll
            for (int ot = 0; ot < 4; ++ot) {
                int row = w * 64 + ot * 16 + l15;
                int ch  = (kk2 * 4 + l4) ^ (row & 7);
                bf[ot] = *(const f16x8*)((const char*)Wl + row * 128 + ch * 16);
            }
#pragma unroll
            for (int nt = 0; nt < 4; ++nt)
#pragma unroll
                for (int ot = 0; ot < 4; ++ot)
                    acc[nt * 4 + ot] = MFMA16(a[nt], bf[ot], acc[nt * 4 + ot]);
        }
    }

    __syncthreads();

    if (mode <= 1) {
        _Float16* Dl = (_Float16*)sm;
#pragma unroll
        for (int nt = 0; nt < 4; ++nt)
#pragma unroll
            for (int ot = 0; ot < 4; ++ot)
#pragma unroll
                for (int reg = 0; reg < 4; ++reg)
                    Dl[(nt * 16 + 4 * l4 + reg) * 256 + w * 64 + ot * 16 + l15] =
                        (_Float16)(acc[nt * 4 + ot][reg] + bias_o[ot]);
        __syncthreads();
        char* dst = (char*)(OUT + ((size_t)b * NTOK + n0) * CDIM);
#pragma unroll
        for (int u = 0; u < 8; ++u) {
            f16x8 v = *(const f16x8*)((const char*)Dl + u * 4096 + tid * 16);
            *(f16x8*)(dst + u * 4096 + tid * 16) = v;
        }
    } else {
        _Float16* Dlv = (_Float16*)sm;   // [256][80]
#pragma unroll
        for (int nt = 0; nt < 4; ++nt)
#pragma unroll
            for (int ot = 0; ot < 4; ++ot)
#pragma unroll
                for (int reg = 0; reg < 4; ++reg)
                    Dlv[(w * 64 + ot * 16 + l15) * 80 + nt * 16 + 4 * l4 + reg] =
                        (_Float16)(acc[nt * 4 + ot][reg] + bias_o[ot]);
        __syncthreads();
#pragma unroll
        for (int t = 0; t < 8; ++t) {
            int ro = (w * 8 + t) * 8 + (lane >> 3);
            f16x8 v = *(const f16x8*)((const char*)Dlv + ro * 160 + (lane & 7) * 16);
            *(f16x8*)(OUT + ((size_t)b * CDIM + ro) * NTOK + n0 + (lane & 7) * 8) = v;
        }
    }
}

// ---------------------------------------------------------------------------
// Split-KV MFMA flash attention — round-6 config (KVBLK=64, full dbuf, 144KB,
// 8 waves, 1 blk/CU) + two deltas:
//  * l-via-MFMA: row-sum l accumulated as a 17th accumulator accl =
//    MFMA(pa, ones, accl) — removes the 16 __shfl_xor ps-reduce DS ops and
//    their serial chains per wave-iteration; rescale path identical to acc.
//  * SEG=3: 432 blocks x 12 iters -> makespan 24 iter-units (vs 27 at SEG=4),
//    and merge traffic 226 -> 188 MB.
// ---------------------------------------------------------------------------
template <int SEG>
__global__ __launch_bounds__(512, 2) void attn_fa(
    const _Float16* __restrict__ Q, const _Float16* __restrict__ K,
    const _Float16* __restrict__ Vt, _Float16* __restrict__ pacc,
    float2* __restrict__ pml)
{
    const int tid  = threadIdx.x;
    const int lane = tid & 63;
    const int w    = tid >> 6;
    const int l15  = lane & 15, l4 = lane >> 4;

    // bijective XCD-chunked swizzle (grid % 8 == 0)
    const int nb  = 18 * BATCH * SEG, cpx = nb / 8;
    const int bid = blockIdx.x;
    const int swz = (bid & 7) * cpx + (bid >> 3);
    const int x = swz % 18;
    const int b = (swz / 18) & 7;
    const int z = swz / 144;

    const int row0   = x * 128 + w * 16;
    const int jbase  = z * (NTOK / SEG);
    const int NTILES = NTOK / SEG / 64;

    __shared__ __align__(16) char smem[147456];   // 144KB
    _Float16* Pw = (_Float16*)(smem + 131072 + w * 2048);

    const size_t kbb = (size_t)b * NTOK;
    const size_t vbb = (size_t)b * CDIM * NTOK;

    auto stage = [&](int j0, int buf) {
        char* Klc = smem + buf * 65536;
        char* Vlc = Klc + 32768;
#pragma unroll
        for (int t = 0; t < 4; ++t) {
            int i = w * 4 + t;
            int krow = 2 * i + (lane >> 5);
            int chunk = lane & 31;
            gl_lds16(K + (kbb + j0 + krow) * CDIM + ((chunk ^ (krow & 7)) * 8),
                     Klc + i * 1024);
        }
#pragma unroll
        for (int t = 0; t < 4; ++t) {
            int i = w * 4 + t;
            int vrow = 8 * i + (lane >> 3);
            int chunk = lane & 7;
            gl_lds16(Vt + vbb + (size_t)vrow * NTOK + j0 + ((chunk ^ (vrow & 7)) * 8),
                     Vlc + i * 1024);
        }
    };

    // Q fragments: 16 rows x 256 c (nontemporal single-use stream)
    f16x8 qa[8];
    {
        const _Float16* qb = Q + ((size_t)b * NTOK + row0 + l15) * CDIM + l4 * 8;
#pragma unroll
        for (int kk = 0; kk < 8; ++kk)
            qa[kk] = __builtin_nontemporal_load((const f16x8*)(qb + kk * 32));
    }

    f32x4 acc[16];
#pragma unroll
    for (int ct = 0; ct < 16; ++ct) acc[ct] = (f32x4){0.f, 0.f, 0.f, 0.f};
    f32x4 accl = (f32x4){0.f, 0.f, 0.f, 0.f};     // row-sums l (17th accum)
    float m[4] = {-FLT_MAX, -FLT_MAX, -FLT_MAX, -FLT_MAX};

    const f16x8 vone = {(_Float16)1.f, (_Float16)1.f, (_Float16)1.f, (_Float16)1.f,
                        (_Float16)1.f, (_Float16)1.f, (_Float16)1.f, (_Float16)1.f};

    // prologue: stage tile 0 into buf 0
    stage(jbase, 0);
    __syncthreads();

    for (int jt = 0; jt < NTILES; ++jt) {
        const int cur = jt & 1;

        if (jt + 1 < NTILES) stage(jbase + (jt + 1) * 64, cur ^ 1);

        const char* Klc = (const char*)smem + cur * 65536;
        const char* Vlc = Klc + 32768;

        // ---- QK^T ----
        f32x4 s[4];
#pragma unroll
        for (int nt = 0; nt < 4; ++nt) {
            const char* kb = Klc + (nt * 16 + l15) * 512;
            f32x4 sv = (f32x4){0.f, 0.f, 0.f, 0.f};
#pragma unroll
            for (int kk = 0; kk < 8; ++kk) {
                f16x8 kf = *(const f16x8*)(kb + (((kk * 4 + l4) ^ (l15 & 7)) * 16));
                sv = MFMA16(qa[kk], kf, sv);
            }
            s[nt] = sv;
        }

        // ---- online softmax (rows i = 4*l4 + reg), defer-max THR=8 ----
        // l is NOT reduced here: it comes from accl = MFMA(P, ones) below.
#pragma unroll
        for (int reg = 0; reg < 4; ++reg) {
            float pm = fmaxf(fmaxf(s[0][reg], s[1][reg]),
                             fmaxf(s[2][reg], s[3][reg]));
            pm = fmaxf(pm, __shfl_xor(pm, 1));
            pm = fmaxf(pm, __shfl_xor(pm, 2));
            pm = fmaxf(pm, __shfl_xor(pm, 4));
            pm = fmaxf(pm, __shfl_xor(pm, 8));
            if (pm > m[reg] + 8.f) {
                float sc = __expf(m[reg] - pm);
                m[reg] = pm;
                accl[reg] *= sc;
#pragma unroll
                for (int ct = 0; ct < 16; ++ct) acc[ct][reg] *= sc;
            }
            const int r = 4 * l4 + reg;
#pragma unroll
            for (int nt = 0; nt < 4; ++nt) {
                float p = __expf(s[nt][reg] - m[reg]);
                int j = nt * 16 + l15;
                Pw[r * 64 + ((j >> 3) ^ (r & 7)) * 8 + (j & 7)] = (_Float16)p;
            }
        }

        // wave-private P dependency: drain LDS writes, fence scheduler
        asm volatile("s_waitcnt lgkmcnt(0)" ::: "memory");
        __builtin_amdgcn_sched_barrier(0);

        // ---- PV + l: acc += P*V ; accl += P*1 ----
        f16x8 pa[2];
#pragma unroll
        for (int kc = 0; kc < 2; ++kc)
            pa[kc] = *(const f16x8*)((const char*)Pw + l15 * 128
                                     + (((kc * 4 + l4) ^ (l15 & 7)) * 16));
        accl = MFMA16(pa[0], vone, accl);
        accl = MFMA16(pa[1], vone, accl);
#pragma unroll
        for (int ct = 0; ct < 16; ++ct) {
            const char* vb0 = Vlc + (ct * 16 + l15) * 128;
#pragma unroll
            for (int kc = 0; kc < 2; ++kc) {
                f16x8 vb = *(const f16x8*)(vb0 + (((kc * 4 + l4) ^ (l15 & 7)) * 16));
                acc[ct] = MFMA16(pa[kc], vb, acc[ct]);
            }
        }

        // drain own staging loads + barrier: next buffer landed, cur released
        __syncthreads();
    }

    // ---- epilogue: LDS-staged, plain linear 16B/lane pacc stores ----
    _Float16* stg = (_Float16*)(smem + w * 8192);
#pragma unroll
    for (int reg = 0; reg < 4; ++reg) {
        float inv = 1.f / accl[reg];
        int r = 4 * l4 + reg;
#pragma unroll
        for (int ct = 0; ct < 16; ++ct)
            stg[r * 256 + ct * 16 + l15] = (_Float16)(acc[ct][reg] * inv);
        if (l15 == 0)
            pml[((size_t)z * BATCH + b) * NTOK + row0 + r] =
                make_float2(m[reg], accl[reg]);
    }
    asm volatile("s_waitcnt lgkmcnt(0)" ::: "memory");
    __builtin_amdgcn_sched_barrier(0);
    {
        const char* stgc = (const char*)stg;
        char* dst = (char*)(pacc + ((size_t)z * BATCH + b) * NTOK * CDIM
                            + (size_t)row0 * CDIM);
#pragma unroll
        for (int u = 0; u < 8; ++u) {
            f16x8 v = *(const f16x8*)(stgc + u * 1024 + lane * 16);
            *(f16x8*)(dst + u * 1024 + lane * 16) = v;
        }
    }
}

// ---------------------------------------------------------------------------
// Merge (unchanged, verified)
// ---------------------------------------------------------------------------
template <int SEG>
__global__ __launch_bounds__(256) void merge_kernel(
    const _Float16* __restrict__ pacc, const float2* __restrict__ pml,
    float* __restrict__ out)
{
    const int tid = threadIdx.x;
    const int n0 = blockIdx.x * 64;
    const int b  = blockIdx.y;

    __shared__ float wgt[SEG][64];
    __shared__ float dinv[64];
    __shared__ float T[64][68];

    if (tid < 64) {
        int n = n0 + tid;
        float ms[SEG], ls[SEG];
#pragma unroll
        for (int s = 0; s < SEG; ++s) {
            float2 v = pml[((size_t)s * BATCH + b) * NTOK + n];
            ms[s] = v.x; ls[s] = v.y;
        }
        float M = ms[0];
#pragma unroll
        for (int s = 1; s < SEG; ++s) M = fmaxf(M, ms[s]);
        float den = 0.f;
#pragma unroll
        for (int s = 0; s < SEG; ++s) {
            float g = ls[s] * __expf(ms[s] - M);
            wgt[s][tid] = g;
            den += g;
        }
        dinv[tid] = 1.f / den;
    }
    __syncthreads();

    for (int cc = 0; cc < 4; ++cc) {
        const int nl = tid >> 2, cg = (tid & 3) * 16;
        float a[16];
#pragma unroll
        for (int u = 0; u < 16; ++u) a[u] = 0.f;
#pragma unroll
        for (int s = 0; s < SEG; ++s) {
            const _Float16* p = pacc + (((size_t)s * BATCH + b) * NTOK + n0 + nl) * CDIM
                                + cc * 64 + cg;
            f16x8 v0 = ((const f16x8*)p)[0];
            f16x8 v1 = ((const f16x8*)p)[1];
            float g = wgt[s][nl];
#pragma unroll
            for (int u = 0; u < 8; ++u) {
                a[u]     += g * (float)v0[u];
                a[8 + u] += g * (float)v1[u];
            }
        }
        float di = dinv[nl];
#pragma unroll
        for (int u = 0; u < 16; ++u) T[nl][cg + u] = a[u] * di;
        __syncthreads();

        const int cl = tid >> 2, nb2 = (tid & 3) * 16;
        float* ob = out + ((size_t)b * CDIM + cc * 64 + cl) * NTOK + n0 + nb2;
#pragma unroll
        for (int u = 0; u < 4; ++u) {
            float4 v = { T[nb2 + u * 4 + 0][cl], T[nb2 + u * 4 + 1][cl],
                         T[nb2 + u * 4 + 2][cl], T[nb2 + u * 4 + 3][cl] };
            *(float4*)&ob[u * 4] = v;
        }
        __syncthreads();
    }
}

// ---------------------------------------------------------------------------
extern "C" void kernel_launch(void* const* d_in, const int* in_sizes, int n_in,
                              void* d_out, int out_size, void* d_ws, size_t ws_size,
                              hipStream_t stream)
{
    const float* x1 = (const float*)d_in[0];
    const float* x2 = (const float*)d_in[1];
    const float* Wq = (const float*)d_in[2];
    const float* bq = (const float*)d_in[3];
    const float* Wk = (const float*)d_in[4];
    const float* bk = (const float*)d_in[5];
    const float* Wv = (const float*)d_in[6];
    const float* bv = (const float*)d_in[7];
    float* out = (float*)d_out;

    const size_t plane = (size_t)BATCH * NTOK * CDIM;   // 4,718,592
    _Float16* ws16 = (_Float16*)d_ws;
    _Float16* Q   = ws16;
    _Float16* K   = ws16 + plane;
    _Float16* Vt  = ws16 + 2 * plane;
    _Float16* Xt1 = ws16 + 3 * plane;
    _Float16* Xt2 = ws16 + 4 * plane;
    _Float16* Wh  = ws16 + 5 * plane;
    const size_t fixed16 = 5 * plane + 196608;

    auto need = [&](size_t S) {
        return fixed16 * 2 + S * plane * 2 + S * (size_t)BATCH * NTOK * 8;
    };
    const int SEG = (ws_size >= need(3)) ? 3 : (ws_size >= need(2)) ? 2 : 1;

    _Float16* pacc = ws16 + fixed16;
    float2*   pml  = (float2*)((char*)d_ws + fixed16 * 2 + (size_t)SEG * plane * 2);

    cast_w<<<dim3(192), dim3(256), 0, stream>>>(Wq, Wk, Wv, Wh);
    cast_x<<<dim3(36, 4, 16), dim3(256), 0, stream>>>(x1, x2, Xt1, Xt2);
    proj_mfma<<<dim3(36, 3, BATCH), dim3(256), 0, stream>>>(
        Xt1, Xt2, Wh, bq, bk, bv, Q, K, Vt);

    const int nb = 18 * BATCH;
    if (SEG == 3) {
        attn_fa<3><<<dim3(nb * 3), dim3(512), 0, stream>>>(Q, K, Vt, pacc, pml);
        merge_kernel<3><<<dim3(36, BATCH), dim3(256), 0, stream>>>(pacc, pml, out);
    } else if (SEG == 2) {
        attn_fa<2><<<dim3(nb * 2), dim3(512), 0, stream>>>(Q, K, Vt, pacc, pml);
        merge_kernel<2><<<dim3(36, BATCH), dim3(256), 0, stream>>>(pacc, pml, out);
    } else {
        attn_fa<1><<<dim3(nb), dim3(512), 0, stream>>>(Q, K, Vt, pacc, pml);
        merge_kernel<1><<<dim3(36, BATCH), dim3(256), 0, stream>>>(pacc, pml, out);
    }
}

// Round 10
// 121.175 us; speedup vs baseline: 3.4775x; 1.1031x over previous
//
#include <hip/hip_runtime.h>
#include <cfloat>
#include <cstddef>
#include <cstdint>

#define BATCH 8
#define CDIM  256
#define NTOK  2304   // 48*48

typedef float    f32x4 __attribute__((ext_vector_type(4)));
typedef _Float16 f16x8 __attribute__((ext_vector_type(8)));
typedef _Float16 f16x4 __attribute__((ext_vector_type(4)));

#define MFMA16(a, b, c) __builtin_amdgcn_mfma_f32_16x16x32_f16(a, b, c, 0, 0, 0)

__device__ __forceinline__ void gl_lds16(const void* g, void* l) {
    __builtin_amdgcn_global_load_lds(
        (const __attribute__((address_space(1))) void*)g,
        (__attribute__((address_space(3))) void*)l, 16, 0, 0);
}

// ---------------------------------------------------------------------------
// cast_w: Wq|Wk|Wv fp32 -> Wh fp16 [3][256][256]   (unchanged, verified)
// ---------------------------------------------------------------------------
__global__ __launch_bounds__(256) void cast_w(
    const float* __restrict__ Wq, const float* __restrict__ Wk,
    const float* __restrict__ Wv, _Float16* __restrict__ Wh)
{
    int i = (blockIdx.x * 256 + threadIdx.x) * 4;
    const float* src = (i < 65536) ? (Wq + i)
                     : (i < 131072) ? (Wk + (i - 65536)) : (Wv + (i - 131072));
    float4 v = *(const float4*)src;
    f16x4 h = { (_Float16)v.x, (_Float16)v.y, (_Float16)v.z, (_Float16)v.w };
    *(f16x4*)(Wh + i) = h;
}

// ---------------------------------------------------------------------------
// cast_x: x [B,C,N] fp32 -> Xt [B,N,C] fp16   (unchanged, verified)
// ---------------------------------------------------------------------------
__global__ __launch_bounds__(256) void cast_x(
    const float* __restrict__ x1, const float* __restrict__ x2,
    _Float16* __restrict__ Xt1, _Float16* __restrict__ Xt2)
{
    const int tid = threadIdx.x;
    const int n0 = blockIdx.x * 64;
    const int c0 = blockIdx.y * 64;
    const int bz = blockIdx.z;
    const float* X   = (bz < 8) ? x1 : x2;
    _Float16*   Xt   = (bz < 8) ? Xt1 : Xt2;
    const int b = bz & 7;

    __shared__ _Float16 T[64][72];

    {
        const int cl = tid >> 2, nch = (tid & 3) * 16;
        const float* src = X + (size_t)(b * CDIM + c0 + cl) * NTOK + n0 + nch;
#pragma unroll
        for (int u = 0; u < 4; ++u) {
            float4 v = *(const float4*)(src + u * 4);
            T[cl][nch + u * 4 + 0] = (_Float16)v.x;
            T[cl][nch + u * 4 + 1] = (_Float16)v.y;
            T[cl][nch + u * 4 + 2] = (_Float16)v.z;
            T[cl][nch + u * 4 + 3] = (_Float16)v.w;
        }
    }
    __syncthreads();
    {
        const int nl = tid >> 2, cch = (tid & 3) * 16;
        _Float16* dst = Xt + (size_t)(b * NTOK + n0 + nl) * CDIM + c0 + cch;
        f16x8 o0, o1;
#pragma unroll
        for (int i = 0; i < 8; ++i) {
            o0[i] = T[cch + i][nl];
            o1[i] = T[cch + 8 + i][nl];
        }
        *(f16x8*)dst = o0;
        *(f16x8*)(dst + 8) = o1;
    }
}

// ---------------------------------------------------------------------------
// proj_mfma   (unchanged, verified)
// ---------------------------------------------------------------------------
__global__ __launch_bounds__(256, 2) void proj_mfma(
    const _Float16* __restrict__ Xt1, const _Float16* __restrict__ Xt2,
    const _Float16* __restrict__ Wh,
    const float* __restrict__ bq, const float* __restrict__ bk,
    const float* __restrict__ bv,
    _Float16* __restrict__ Qo, _Float16* __restrict__ Ko, _Float16* __restrict__ Vo)
{
    const int tid  = threadIdx.x;
    const int lane = tid & 63;
    const int w    = tid >> 6;
    const int l15  = lane & 15, l4 = lane >> 4;
    const int n0   = blockIdx.x * 64;
    const int mode = blockIdx.y;
    const int b    = blockIdx.z;

    const _Float16* Xt = (mode == 0) ? Xt1 : Xt2;
    const _Float16* Wm = Wh + mode * 65536;
    const float* bias  = (mode == 0) ? bq : (mode == 1) ? bk : bv;
    _Float16* OUT      = (mode == 0) ? Qo : (mode == 1) ? Ko : Vo;

    __shared__ __align__(16) char sm[65536];
    _Float16* Xl = (_Float16*)sm;
    _Float16* Wl = (_Float16*)(sm + 32768);

#pragma unroll
    for (int t = 0; t < 8; ++t) {
        int i = w * 8 + t;
        int row = 2 * i + (lane >> 5);
        int ch  = lane & 31;
        gl_lds16(Xt + (size_t)(b * NTOK + n0 + row) * CDIM + ((ch ^ (row & 7)) * 8),
                 (char*)Xl + i * 1024);
    }

    float bias_o[4];
#pragma unroll
    for (int ot = 0; ot < 4; ++ot) bias_o[ot] = bias[w * 64 + ot * 16 + l15];

    f32x4 acc[16];
#pragma unroll
    for (int i = 0; i < 16; ++i) acc[i] = (f32x4){0.f, 0.f, 0.f, 0.f};

    for (int c0 = 0; c0 < CDIM; c0 += 64) {
        __syncthreads();
#pragma unroll
        for (int t = 0; t < 8; ++t) {
            int i = w * 8 + t;
            int row = 8 * i + (lane >> 3);
            int ch  = lane & 7;
            gl_lds16(Wm + (size_t)row * CDIM + c0 + ((ch ^ (row & 7)) * 8),
                     (char*)Wl + i * 1024);
        }
        __syncthreads();

#pragma unroll
        for (int kk2 = 0; kk2 < 2; ++kk2) {
            f16x8 a[4], bf[4];
#pragma unroll
            for (int nt = 0; nt < 4; ++nt) {
                int row = nt * 16 + l15;
                int ch  = ((c0 >> 3) + kk2 * 4 + l4) ^ (row & 7);
                a[nt] = *(const f16x8*)((const char*)Xl + row * 512 + ch * 16);
            }
#pragma unroll
            for (int ot = 0; ot < 4; ++ot) {
                int row = w * 64 + ot * 16 + l15;
                int ch  = (kk2 * 4 + l4) ^ (row & 7);
                bf[ot] = *(const f16x8*)((const char*)Wl + row * 128 + ch * 16);
            }
#pragma unroll
            for (int nt = 0; nt < 4; ++nt)
#pragma unroll
                for (int ot = 0; ot < 4; ++ot)
                    acc[nt * 4 + ot] = MFMA16(a[nt], bf[ot], acc[nt * 4 + ot]);
        }
    }

    __syncthreads();

    if (mode <= 1) {
        _Float16* Dl = (_Float16*)sm;
#pragma unroll
        for (int nt = 0; nt < 4; ++nt)
#pragma unroll
            for (int ot = 0; ot < 4; ++ot)
#pragma unroll
                for (int reg = 0; reg < 4; ++reg)
                    Dl[(nt * 16 + 4 * l4 + reg) * 256 + w * 64 + ot * 16 + l15] =
                        (_Float16)(acc[nt * 4 + ot][reg] + bias_o[ot]);
        __syncthreads();
        char* dst = (char*)(OUT + ((size_t)b * NTOK + n0) * CDIM);
#pragma unroll
        for (int u = 0; u < 8; ++u) {
            f16x8 v = *(const f16x8*)((const char*)Dl + u * 4096 + tid * 16);
            *(f16x8*)(dst + u * 4096 + tid * 16) = v;
        }
    } else {
        _Float16* Dlv = (_Float16*)sm;   // [256][80]
#pragma unroll
        for (int nt = 0; nt < 4; ++nt)
#pragma unroll
            for (int ot = 0; ot < 4; ++ot)
#pragma unroll
                for (int reg = 0; reg < 4; ++reg)
                    Dlv[(w * 64 + ot * 16 + l15) * 80 + nt * 16 + 4 * l4 + reg] =
                        (_Float16)(acc[nt * 4 + ot][reg] + bias_o[ot]);
        __syncthreads();
#pragma unroll
        for (int t = 0; t < 8; ++t) {
            int ro = (w * 8 + t) * 8 + (lane >> 3);
            f16x8 v = *(const f16x8*)((const char*)Dlv + ro * 160 + (lane & 7) * 16);
            *(f16x8*)(OUT + ((size_t)b * CDIM + ro) * NTOK + n0 + (lane & 7) * 8) = v;
        }
    }
}

// ---------------------------------------------------------------------------
// Split-KV MFMA flash attention — SWAPPED-OPERAND form (T12-style), no P LDS.
//  * QK^T computed as mfma(K, Q) -> S^T: q = lane&15 is lane-local.
//    Softmax: 15-fmax chain + 2 shfl (was 16 shfl); m/l/acc per-lane uniform.
//  * K-tile rows staged PERMUTED by sigma (bit-permutation, free: whole rows)
//    so each lane's computed P values are exactly its PV B-fragment elements:
//    pa[kc][e] = exp(s[2kc+(e>>2)][e&3] - m). No P LDS write/read at all.
//    sigma(lr) = (lr&32) | ((lr&12)<<1) | ((lr&16)>>2) | (lr&3);
//    element-verified: label 57 -> j 53 = kc1,l4=2,e=5 etc.
//  * PV as mfma(V, P): acc[ct] holds (c = ct*16 + 4*l4 + reg, q = lane&15).
//  * l via accl = mfma(ones, pa) (rows all equal l(q)).
// LDS = 128KB (2 x {K 32K + V 32K} dbuf). DS ops/wave-iter: 98 -> 66.
// ---------------------------------------------------------------------------
template <int SEG>
__global__ __launch_bounds__(512, 2) void attn_fa(
    const _Float16* __restrict__ Q, const _Float16* __restrict__ K,
    const _Float16* __restrict__ Vt, _Float16* __restrict__ pacc,
    float2* __restrict__ pml)
{
    const int tid  = threadIdx.x;
    const int lane = tid & 63;
    const int w    = tid >> 6;
    const int l15  = lane & 15, l4 = lane >> 4;

    // bijective XCD-chunked swizzle (grid % 8 == 0)
    const int nb  = 18 * BATCH * SEG, cpx = nb / 8;
    const int bid = blockIdx.x;
    const int swz = (bid & 7) * cpx + (bid >> 3);
    const int x = swz % 18;
    const int b = (swz / 18) & 7;
    const int z = swz / 144;

    const int row0   = x * 128 + w * 16;
    const int jbase  = z * (NTOK / SEG);
    const int NTILES = NTOK / SEG / 64;

    __shared__ __align__(16) char smem[131072];   // 128KB

    const size_t kbb = (size_t)b * NTOK;
    const size_t vbb = (size_t)b * CDIM * NTOK;

    auto stage = [&](int j0, int buf) {
        char* Klc = smem + buf * 65536;
        char* Vlc = Klc + 32768;
        // K: LDS row lr holds GLOBAL row sigma(lr); rows contiguous 512B.
#pragma unroll
        for (int t = 0; t < 4; ++t) {
            int i  = w * 4 + t;
            int lr = 2 * i + (lane >> 5);
            int gr = (lr & 32) | ((lr & 12) << 1) | ((lr & 16) >> 2) | (lr & 3);
            int chunk = lane & 31;
            gl_lds16(K + (kbb + j0 + gr) * CDIM + ((chunk ^ (lr & 7)) * 8),
                     Klc + i * 1024);
        }
        // V: unchanged (linear j columns, c-row swizzle) — verified r9.
#pragma unroll
        for (int t = 0; t < 4; ++t) {
            int i = w * 4 + t;
            int vrow = 8 * i + (lane >> 3);
            int chunk = lane & 7;
            gl_lds16(Vt + vbb + (size_t)vrow * NTOK + j0 + ((chunk ^ (vrow & 7)) * 8),
                     Vlc + i * 1024);
        }
    };

    // Q fragments: 16 rows x 256 c (nontemporal single-use stream)
    f16x8 qa[8];
    {
        const _Float16* qb = Q + ((size_t)b * NTOK + row0 + l15) * CDIM + l4 * 8;
#pragma unroll
        for (int kk = 0; kk < 8; ++kk)
            qa[kk] = __builtin_nontemporal_load((const f16x8*)(qb + kk * 32));
    }

    f32x4 acc[16];
#pragma unroll
    for (int ct = 0; ct < 16; ++ct) acc[ct] = (f32x4){0.f, 0.f, 0.f, 0.f};
    f32x4 accl = (f32x4){0.f, 0.f, 0.f, 0.f};
    float m = -FLT_MAX;                     // per-lane: q = row0 + l15

    const f16x8 vone = {(_Float16)1.f, (_Float16)1.f, (_Float16)1.f, (_Float16)1.f,
                        (_Float16)1.f, (_Float16)1.f, (_Float16)1.f, (_Float16)1.f};

    stage(jbase, 0);
    __syncthreads();

    for (int jt = 0; jt < NTILES; ++jt) {
        const int cur = jt & 1;

        if (jt + 1 < NTILES) stage(jbase + (jt + 1) * 64, cur ^ 1);

        const char* Klc = (const char*)smem + cur * 65536;
        const char* Vlc = Klc + 32768;

        // ---- QK^T swapped: s[nt] = S^T[label = nt*16+4*l4+reg][q = l15] ----
        f32x4 s[4];
#pragma unroll
        for (int nt = 0; nt < 4; ++nt) {
            const char* kb = Klc + (nt * 16 + l15) * 512;
            f32x4 sv = (f32x4){0.f, 0.f, 0.f, 0.f};
#pragma unroll
            for (int kk = 0; kk < 8; ++kk) {
                f16x8 kf = *(const f16x8*)(kb + (((kk * 4 + l4) ^ (l15 & 7)) * 16));
                sv = MFMA16(kf, qa[kk], sv);        // SWAPPED
            }
            s[nt] = sv;
        }

        // ---- softmax: lane-local max chain + 2 shfl; defer-max THR=8 ----
        float pm = fmaxf(fmaxf(s[0][0], s[0][1]), fmaxf(s[0][2], s[0][3]));
        pm = fmaxf(pm, fmaxf(fmaxf(s[1][0], s[1][1]), fmaxf(s[1][2], s[1][3])));
        pm = fmaxf(pm, fmaxf(fmaxf(s[2][0], s[2][1]), fmaxf(s[2][2], s[2][3])));
        pm = fmaxf(pm, fmaxf(fmaxf(s[3][0], s[3][1]), fmaxf(s[3][2], s[3][3])));
        pm = fmaxf(pm, __shfl_xor(pm, 16));
        pm = fmaxf(pm, __shfl_xor(pm, 32));
        if (pm > m + 8.f) {
            float sc = __expf(m - pm);
            m = pm;
#pragma unroll
            for (int e = 0; e < 4; ++e) accl[e] *= sc;
#pragma unroll
            for (int ct = 0; ct < 16; ++ct)
#pragma unroll
                for (int e = 0; e < 4; ++e) acc[ct][e] *= sc;
        }

        // ---- P in registers (lane-local, via K-row permutation) ----
        f16x8 pa[2];
#pragma unroll
        for (int kc = 0; kc < 2; ++kc)
#pragma unroll
            for (int e = 0; e < 8; ++e)
                pa[kc][e] = (_Float16)__expf(s[2 * kc + (e >> 2)][e & 3] - m);

        // ---- l and PV (both swapped: acc (c = 4*l4+reg, q = l15)) ----
        accl = MFMA16(vone, pa[0], accl);
        accl = MFMA16(vone, pa[1], accl);
#pragma unroll
        for (int ct = 0; ct < 16; ++ct) {
            const char* vb0 = Vlc + (ct * 16 + l15) * 128;
#pragma unroll
            for (int kc = 0; kc < 2; ++kc) {
                f16x8 vb = *(const f16x8*)(vb0 + (((kc * 4 + l4) ^ (l15 & 7)) * 16));
                acc[ct] = MFMA16(vb, pa[kc], acc[ct]);   // SWAPPED
            }
        }

        __syncthreads();
    }

    // ---- epilogue: stg [16 q][264 f16] (padded) -> linear pacc stores ----
    _Float16* stg = (_Float16*)(smem + w * 8448);
    {
        float inv = 1.f / accl[0];
#pragma unroll
        for (int ct = 0; ct < 16; ++ct) {
            f16x4 o = { (_Float16)(acc[ct][0] * inv), (_Float16)(acc[ct][1] * inv),
                        (_Float16)(acc[ct][2] * inv), (_Float16)(acc[ct][3] * inv) };
            *(f16x4*)&stg[l15 * 264 + ct * 16 + l4 * 4] = o;
        }
        if (l4 == 0)
            pml[((size_t)z * BATCH + b) * NTOK + row0 + l15] =
                make_float2(m, accl[0]);
    }
    asm volatile("s_waitcnt lgkmcnt(0)" ::: "memory");
    __builtin_amdgcn_sched_barrier(0);
    {
        const char* stgc = (const char*)stg;
        char* dst = (char*)(pacc + ((size_t)z * BATCH + b) * NTOK * CDIM
                            + (size_t)row0 * CDIM);
#pragma unroll
        for (int u = 0; u < 8; ++u) {
            int r = 2 * u + (lane >> 5);
            f16x8 v = *(const f16x8*)(stgc + r * 528 + (lane & 31) * 16);
            *(f16x8*)(dst + r * 512 + (lane & 31) * 16) = v;
        }
    }
}

// ---------------------------------------------------------------------------
// Merge (unchanged, verified)
// ---------------------------------------------------------------------------
template <int SEG>
__global__ __launch_bounds__(256) void merge_kernel(
    const _Float16* __restrict__ pacc, const float2* __restrict__ pml,
    float* __restrict__ out)
{
    const int tid = threadIdx.x;
    const int n0 = blockIdx.x * 64;
    const int b  = blockIdx.y;

    __shared__ float wgt[SEG][64];
    __shared__ float dinv[64];
    __shared__ float T[64][68];

    if (tid < 64) {
        int n = n0 + tid;
        float ms[SEG], ls[SEG];
#pragma unroll
        for (int s = 0; s < SEG; ++s) {
            float2 v = pml[((size_t)s * BATCH + b) * NTOK + n];
            ms[s] = v.x; ls[s] = v.y;
        }
        float M = ms[0];
#pragma unroll
        for (int s = 1; s < SEG; ++s) M = fmaxf(M, ms[s]);
        float den = 0.f;
#pragma unroll
        for (int s = 0; s < SEG; ++s) {
            float g = ls[s] * __expf(ms[s] - M);
            wgt[s][tid] = g;
            den += g;
        }
        dinv[tid] = 1.f / den;
    }
    __syncthreads();

    for (int cc = 0; cc < 4; ++cc) {
        const int nl = tid >> 2, cg = (tid & 3) * 16;
        float a[16];
#pragma unroll
        for (int u = 0; u < 16; ++u) a[u] = 0.f;
#pragma unroll
        for (int s = 0; s < SEG; ++s) {
            const _Float16* p = pacc + (((size_t)s * BATCH + b) * NTOK + n0 + nl) * CDIM
                                + cc * 64 + cg;
            f16x8 v0 = ((const f16x8*)p)[0];
            f16x8 v1 = ((const f16x8*)p)[1];
            float g = wgt[s][nl];
#pragma unroll
            for (int u = 0; u < 8; ++u) {
                a[u]     += g * (float)v0[u];
                a[8 + u] += g * (float)v1[u];
            }
        }
        float di = dinv[nl];
#pragma unroll
        for (int u = 0; u < 16; ++u) T[nl][cg + u] = a[u] * di;
        __syncthreads();

        const int cl = tid >> 2, nb2 = (tid & 3) * 16;
        float* ob = out + ((size_t)b * CDIM + cc * 64 + cl) * NTOK + n0 + nb2;
#pragma unroll
        for (int u = 0; u < 4; ++u) {
            float4 v = { T[nb2 + u * 4 + 0][cl], T[nb2 + u * 4 + 1][cl],
                         T[nb2 + u * 4 + 2][cl], T[nb2 + u * 4 + 3][cl] };
            *(float4*)&ob[u * 4] = v;
        }
        __syncthreads();
    }
}

// ---------------------------------------------------------------------------
extern "C" void kernel_launch(void* const* d_in, const int* in_sizes, int n_in,
                              void* d_out, int out_size, void* d_ws, size_t ws_size,
                              hipStream_t stream)
{
    const float* x1 = (const float*)d_in[0];
    const float* x2 = (const float*)d_in[1];
    const float* Wq = (const float*)d_in[2];
    const float* bq = (const float*)d_in[3];
    const float* Wk = (const float*)d_in[4];
    const float* bk = (const float*)d_in[5];
    const float* Wv = (const float*)d_in[6];
    const float* bv = (const float*)d_in[7];
    float* out = (float*)d_out;

    const size_t plane = (size_t)BATCH * NTOK * CDIM;   // 4,718,592
    _Float16* ws16 = (_Float16*)d_ws;
    _Float16* Q   = ws16;
    _Float16* K   = ws16 + plane;
    _Float16* Vt  = ws16 + 2 * plane;
    _Float16* Xt1 = ws16 + 3 * plane;
    _Float16* Xt2 = ws16 + 4 * plane;
    _Float16* Wh  = ws16 + 5 * plane;
    const size_t fixed16 = 5 * plane + 196608;

    auto need = [&](size_t S) {
        return fixed16 * 2 + S * plane * 2 + S * (size_t)BATCH * NTOK * 8;
    };
    const int SEG = (ws_size >= need(3)) ? 3 : (ws_size >= need(2)) ? 2 : 1;

    _Float16* pacc = ws16 + fixed16;
    float2*   pml  = (float2*)((char*)d_ws + fixed16 * 2 + (size_t)SEG * plane * 2);

    cast_w<<<dim3(192), dim3(256), 0, stream>>>(Wq, Wk, Wv, Wh);
    cast_x<<<dim3(36, 4, 16), dim3(256), 0, stream>>>(x1, x2, Xt1, Xt2);
    proj_mfma<<<dim3(36, 3, BATCH), dim3(256), 0, stream>>>(
        Xt1, Xt2, Wh, bq, bk, bv, Q, K, Vt);

    const int nb = 18 * BATCH;
    if (SEG == 3) {
        attn_fa<3><<<dim3(nb * 3), dim3(512), 0, stream>>>(Q, K, Vt, pacc, pml);
        merge_kernel<3><<<dim3(36, BATCH), dim3(256), 0, stream>>>(pacc, pml, out);
    } else if (SEG == 2) {
        attn_fa<2><<<dim3(nb * 2), dim3(512), 0, stream>>>(Q, K, Vt, pacc, pml);
        merge_kernel<2><<<dim3(36, BATCH), dim3(256), 0, stream>>>(pacc, pml, out);
    } else {
        attn_fa<1><<<dim3(nb), dim3(512), 0, stream>>>(Q, K, Vt, pacc, pml);
        merge_kernel<1><<<dim3(36, BATCH), dim3(256), 0, stream>>>(pacc, pml, out);
    }
}